// Round 6
// baseline (1364.462 us; speedup 1.0000x reference)
//
#include <hip/hip_runtime.h>
#include <math.h>

// Problem constants
#define BATCH 262144

// ws layout (float offsets)
#define WF_OFF  0        // [72][256] gate-interleaved fused weights: W_fused[k][u*4+g]
#define BF_OFF  18432    // [256] gate-interleaved bias b_fused[u*4+g]
#define G6_OFF  18944    // [8][8]  C^T diag(1/(R+1e-6)) C
#define G8_OFF  19008    // [8][8]  C^T diag(1/(R+1e-8)) C
#define R6_OFF  19072    // [16] 1/(R+1e-6)
#define R8_OFF  19088    // [16] 1/(R+1e-8)
#define SLR_OFF 19104    // scalar: sum log(R+1e-6)

__device__ __forceinline__ float rcp1(float x) {
    float r = __builtin_amdgcn_rcpf(x);
    return r * (2.0f - x * r);   // one Newton step: ~1e-7 rel err
}
__device__ __forceinline__ float sigm(float x) {
    float e = __expf(-fabsf(x));          // in (0,1], never overflows
    float s = rcp1(1.0f + e);             // sigm(|x|)
    return (x >= 0.0f) ? s : e * s;       // sigm(-|x|) = e*s
}
__device__ __forceinline__ float tanh_f(float x) {
    float e = __expf(-2.0f * fabsf(x));   // in (0,1]
    float t = (1.0f - e) * rcp1(1.0f + e);
    return copysignf(t, x);
}

// ---------------- prep: fuse/permute weights + batch-independent stats -------
__global__ void prep_kernel(const float* __restrict__ Wk,   // [8][256]
                            const float* __restrict__ Wr,   // [64][256]
                            const float* __restrict__ b_lstm,// [256]
                            const float* __restrict__ Cm,   // [16][8]
                            const float* __restrict__ logR, // [16]
                            float* __restrict__ ws) {
    int t = threadIdx.x;   // 0..255 = fused column c = u*4 + g
    int src = (t & 3) * 64 + (t >> 2);   // original column g*64+u
#pragma unroll
    for (int k = 0; k < 8; ++k)  ws[WF_OFF + k * 256 + t]       = Wk[k * 256 + src];
#pragma unroll
    for (int k = 0; k < 64; ++k) ws[WF_OFF + (8 + k) * 256 + t] = Wr[k * 256 + src];
    ws[BF_OFF + t] = b_lstm[src];

    if (t < 64) {
        int k = t >> 3, l = t & 7;
        float g6 = 0.0f, g8 = 0.0f;
        for (int i = 0; i < 16; ++i) {
            float R  = expf(logR[i]);
            float cc = Cm[i * 8 + k] * Cm[i * 8 + l];
            g6 += cc / (R + 1e-6f);
            g8 += cc / (R + 1e-8f);
        }
        ws[G6_OFF + t] = g6;
        ws[G8_OFF + t] = g8;
    } else if (t < 80) {
        int i = t - 64;
        float R = expf(logR[i]);
        ws[R6_OFF + i] = 1.0f / (R + 1e-6f);
        ws[R8_OFF + i] = 1.0f / (R + 1e-8f);
    } else if (t == 80) {
        float s = 0.0f;
        for (int i = 0; i < 16; ++i) s += logf(expf(logR[i]) + 1e-6f);
        ws[SLR_OFF] = s;
    }
}

// ---------------- LSTM kernel: register-tiled GEMM, conflict-free LDS --------
// Block = 256 threads, tile = 64 elements x 256 gate-cols, per-thread 8x8.
// mt = t>>5 (elem group), nt = t&31. Thread owns units u0=nt, u1=nt+32 ->
// B-reads are LINEAR 512B spans (chunks 0..31 / 32..63) -> conflict-free.
// ha staged ROW-major [e][72] (linear float4 writes; A-reads are broadcast).
// LDS = 18432 + 12288 = 30720 B -> 5 blocks/CU.
__global__ __launch_bounds__(256, 5)
void lstm_kernel(const float* __restrict__ h_in,
                 const float* __restrict__ c_in,
                 const float* __restrict__ z_prev,
                 const float* __restrict__ ws,
                 float* __restrict__ out) {
    __shared__ __align__(16) float ha_lds[64 * 72];  // [e][k]: 0-7 z, 8-71 h; reused as c[64][64]
    __shared__ __align__(16) float w_lds[12 * 256];  // K-chunk of W_fused; reused (w/ cbuf) as h_new? no: h_new fits too

    const int t  = threadIdx.x;
    const int mt = t >> 5;     // 0..7
    const int nt = t & 31;     // 0..31
    const int u0 = nt;
    const int u1 = nt + 32;
    const size_t E0 = (size_t)blockIdx.x * 64;
    const float* WF = ws + WF_OFF;

    // ---- stage ha row-major (all linear float4 LDS writes) ----
#pragma unroll
    for (int i = 0; i < 4; ++i) {
        int g = i * 1024 + t * 4;      // 0..4095
        int e = g >> 6, u = g & 63;
        float4 hv = *(const float4*)(h_in + E0 * 64 + g);
        *(float4*)(ha_lds + e * 72 + 8 + u) = hv;
    }
    if (t < 128) {
        int g = t * 4;                 // 0..511
        int e = g >> 3, p = g & 7;
        float4 zv = *(const float4*)(z_prev + E0 * 8 + g);
        *(float4*)(ha_lds + e * 72 + p) = zv;
    }

    float acc[8][8];
#pragma unroll
    for (int j = 0; j < 8; ++j)
#pragma unroll
        for (int c = 0; c < 8; ++c) acc[j][c] = 0.0f;

    // ---- GEMM over K in 6 chunks of 12 ----
#pragma unroll 1
    for (int ch = 0; ch < 6; ++ch) {
        __syncthreads();   // ha staged (ch 0) / previous chunk FMAs done
#pragma unroll
        for (int i = 0; i < 3; ++i) {
            int off = (i * 256 + t) * 4;
            *(float4*)(w_lds + off) = *(const float4*)(WF + ch * (12 * 256) + off);
        }
        __syncthreads();
#pragma unroll
        for (int k4 = 0; k4 < 12; k4 += 4) {
            float4 av[8];
#pragma unroll
            for (int j = 0; j < 8; ++j)
                av[j] = *(const float4*)(ha_lds + (mt * 8 + j) * 72 + ch * 12 + k4);
#pragma unroll
            for (int kk = 0; kk < 4; ++kk) {
                float4 b0 = *(const float4*)(w_lds + (k4 + kk) * 256 + u0 * 4);
                float4 b1 = *(const float4*)(w_lds + (k4 + kk) * 256 + u1 * 4);
#pragma unroll
                for (int j = 0; j < 8; ++j) {
                    float a = (kk == 0) ? av[j].x : (kk == 1) ? av[j].y : (kk == 2) ? av[j].z : av[j].w;
                    acc[j][0] = fmaf(a, b0.x, acc[j][0]);
                    acc[j][1] = fmaf(a, b0.y, acc[j][1]);
                    acc[j][2] = fmaf(a, b0.z, acc[j][2]);
                    acc[j][3] = fmaf(a, b0.w, acc[j][3]);
                    acc[j][4] = fmaf(a, b1.x, acc[j][4]);
                    acc[j][5] = fmaf(a, b1.y, acc[j][5]);
                    acc[j][6] = fmaf(a, b1.z, acc[j][6]);
                    acc[j][7] = fmaf(a, b1.w, acc[j][7]);
                }
            }
        }
    }
    __syncthreads();   // GEMM done; ha_lds / w_lds reusable

    // ---- load c_old into LDS (short live range: load -> immediate store) ----
    float* cbuf = ha_lds;   // [64][64] row-major
    float* hbuf = ha_lds + 16 * 72;  // careful: overlaps cbuf? NO -> use separate mapping below
    // cbuf occupies ha_lds[0 .. 4096); h_new buffer goes in w_lds? w_lds is only
    // 3072 floats < 4096. Put h_new in ha_lds[4096 .. 4608) won't fit either.
    // Solution: ha_lds is 4608 floats total; cbuf needs 4096. Write h_new
    // DIRECTLY to global from registers? Not coalesced. Instead: stage h_new
    // into cbuf region AFTER c_new replaces c? Both needed simultaneously.
    // -> Use w_lds (3072) + ha_lds tail (512+512) split: h_new[e][u] with
    //    e 0..47 in w_lds (48*64=3072), e 48..63 in ha_lds+4096 (16*64=1024
    //    > 512 available!). ha_lds total 64*72=4608; tail after cbuf = 512.
    // Simplest correct: do h/c write-out in TWO passes of 32 elements each,
    // reusing cbuf region: pass A = elems 0..31 (c then h), pass B = 32..63.
    {
        float4 ctmp[4];
#pragma unroll
        for (int i = 0; i < 4; ++i)
            ctmp[i] = *(const float4*)(c_in + E0 * 64 + i * 1024 + t * 4);
#pragma unroll
        for (int i = 0; i < 4; ++i)
            *(float4*)(cbuf + i * 1024 + t * 4) = ctmp[i];
    }
    __syncthreads();

    // ---- nonlinearity in-register: thread owns (u0,u1) x elems mt*8..+7 ----
    const float* BF = ws + BF_OFF;
    const float bi0 = BF[u0 * 4 + 0], bf0 = BF[u0 * 4 + 1], bg0 = BF[u0 * 4 + 2], bo0 = BF[u0 * 4 + 3];
    const float bi1 = BF[u1 * 4 + 0], bf1 = BF[u1 * 4 + 1], bg1 = BF[u1 * 4 + 2], bo1 = BF[u1 * 4 + 3];
    float hn0[8], hn1[8];
#pragma unroll
    for (int j = 0; j < 8; ++j) {
        int e = mt * 8 + j;
        {
            float zi = acc[j][0] + bi0, zf = acc[j][1] + bf0;
            float zg = acc[j][2] + bg0, zo = acc[j][3] + bo0;
            float cold = cbuf[e * 64 + u0];
            float cn = sigm(zf) * cold + sigm(zi) * tanh_f(zg);
            hn0[j] = sigm(zo) * tanh_f(cn);
            cbuf[e * 64 + u0] = cn;   // slot's only reader is this thread
        }
        {
            float zi = acc[j][4] + bi1, zf = acc[j][5] + bf1;
            float zg = acc[j][6] + bg1, zo = acc[j][7] + bo1;
            float cold = cbuf[e * 64 + u1];
            float cn = sigm(zf) * cold + sigm(zi) * tanh_f(zg);
            hn1[j] = sigm(zo) * tanh_f(cn);
            cbuf[e * 64 + u1] = cn;
        }
    }
    __syncthreads();

    // ---- write out c_new (coalesced), then reuse cbuf for h_new ----
    float* outH = out + (size_t)BATCH * 73  + E0 * 64;
    float* outC = out + (size_t)BATCH * 137 + E0 * 64;
#pragma unroll
    for (int i = 0; i < 4; ++i) {
        int g = i * 1024 + t * 4;
        *(float4*)(outC + g) = *(const float4*)(cbuf + g);
    }
    __syncthreads();
#pragma unroll
    for (int j = 0; j < 8; ++j) {
        int e = mt * 8 + j;
        cbuf[e * 64 + u0] = hn0[j];
        cbuf[e * 64 + u1] = hn1[j];
    }
    __syncthreads();
#pragma unroll
    for (int i = 0; i < 4; ++i) {
        int g = i * 1024 + t * 4;
        *(float4*)(outH + g) = *(const float4*)(cbuf + g);
    }
}

// ---------------- tail kernel: mu/lsg GEMM + Gaussian tail -------------------
__global__ __launch_bounds__(256)
void tail_kernel(const float* __restrict__ x_in,
                 const float* __restrict__ W_mu,
                 const float* __restrict__ b_mu,
                 const float* __restrict__ W_ls,
                 const float* __restrict__ b_ls,
                 const float* __restrict__ Cm,
                 const float* __restrict__ b_em,
                 const float* __restrict__ ws,
                 float* __restrict__ out) {
    __shared__ float hn[64 * 65];     // [u][e] h_new tile; reused as V chunk buffer
    __shared__ float muls[16 * 257];  // [d][e256]

    const int t    = threadIdx.x;
    const int lane = t & 63;
    const int wv   = t >> 6;
    const int wvu  = __builtin_amdgcn_readfirstlane(wv);
    const int blk  = blockIdx.x;
    const float* hN = out + (size_t)BATCH * 73;

    for (int tile = 0; tile < 4; ++tile) {
        const size_t E0 = (size_t)blk * 256 + (size_t)tile * 64;
#pragma unroll
        for (int i = 0; i < 4; ++i) {
            int g = i * 1024 + t * 4;
            int e = g >> 6, u = g & 63;
            float4 hv = *(const float4*)(hN + E0 * 64 + g);
            hn[(u + 0) * 65 + e] = hv.x;
            hn[(u + 1) * 65 + e] = hv.y;
            hn[(u + 2) * 65 + e] = hv.z;
            hn[(u + 3) * 65 + e] = hv.w;
        }
        __syncthreads();
        {
            int d0 = wvu * 2;
            float m0 = b_mu[d0], m1 = b_mu[d0 + 1];
            float l0 = b_ls[d0], l1 = b_ls[d0 + 1];
#pragma unroll
            for (int u = 0; u < 64; ++u) {
                float hv = hn[u * 65 + lane];
                m0 = fmaf(hv, W_mu[u * 8 + d0],     m0);
                m1 = fmaf(hv, W_mu[u * 8 + d0 + 1], m1);
                l0 = fmaf(hv, W_ls[u * 8 + d0],     l0);
                l1 = fmaf(hv, W_ls[u * 8 + d0 + 1], l1);
            }
            int col = tile * 64 + lane;
            muls[(d0 + 0) * 257 + col] = m0;
            muls[(d0 + 1) * 257 + col] = m1;
            muls[(8 + d0 + 0) * 257 + col] = l0;
            muls[(8 + d0 + 1) * 257 + col] = l1;
        }
        __syncthreads();
    }

    const float* G6 = ws + G6_OFF;
    const float* G8 = ws + G8_OFF;
    const float* r6 = ws + R6_OFF;
    const float* r8 = ws + R8_OFF;
    const float  slr = ws[SLR_OFF];
    const size_t e = (size_t)blk * 256 + t;

    float mu[8], lsg[8];
#pragma unroll
    for (int d = 0; d < 8; ++d) {
        mu[d]  = muls[d * 257 + t];
        lsg[d] = muls[(8 + d) * 257 + t];
    }

    float sig[8], Sinv[8];
#pragma unroll
    for (int d = 0; d < 8; ++d) {
        float l = fminf(fmaxf(lsg[d], -5.0f), 3.0f);
        float s = __expf(l);
        sig[d]  = s;
        Sinv[d] = rcp1(s * s + 1e-8f);
    }

    float xv[16];
    {
        const float4* x4 = (const float4*)(x_in + e * 16);
#pragma unroll
        for (int q = 0; q < 4; ++q) {
            float4 v = x4[q];
            xv[4 * q + 0] = v.x; xv[4 * q + 1] = v.y;
            xv[4 * q + 2] = v.z; xv[4 * q + 3] = v.w;
        }
    }

    float t6[8], t8[8];
#pragma unroll
    for (int k = 0; k < 8; ++k) { t6[k] = 0.0f; t8[k] = 0.0f; }
    float qdr = 0.0f;
#pragma unroll
    for (int i = 0; i < 16; ++i) {
        float pm = b_em[i];
#pragma unroll
        for (int d = 0; d < 8; ++d) pm = fmaf(mu[d], Cm[i * 8 + d], pm);
        float df = xv[i] - pm;
        float xe = xv[i] - b_em[i];
        float a6 = df * r6[i];
        float a8 = xe * r8[i];
        qdr = fmaf(df, a6, qdr);
#pragma unroll
        for (int k = 0; k < 8; ++k) {
            t6[k] = fmaf(a6, Cm[i * 8 + k], t6[k]);
            t8[k] = fmaf(a8, Cm[i * 8 + k], t8[k]);
        }
    }

    // ---- alpha via Woodbury ----
    float M[8][8];
#pragma unroll
    for (int k = 0; k < 8; ++k)
#pragma unroll
        for (int l = 0; l <= k; ++l)
            M[k][l] = ((k == l) ? 1.0f : 0.0f) + sig[k] * sig[l] * G6[k * 8 + l];

    float ldia[8];
    float logdetM = 0.0f;
#pragma unroll
    for (int k = 0; k < 8; ++k) {
        float d = M[k][k];
#pragma unroll
        for (int j = 0; j < k; ++j) d = fmaf(-M[k][j], M[k][j], d);
        float l = sqrtf(d);
        logdetM += __logf(d);
        float li = rcp1(l);
        M[k][k] = l; ldia[k] = li;
#pragma unroll
        for (int i = k + 1; i < 8; ++i) {
            float s = M[i][k];
#pragma unroll
            for (int j = 0; j < k; ++j) s = fmaf(-M[i][j], M[k][j], s);
            M[i][k] = s * li;
        }
    }
    float w[8];
    float ssq = 0.0f;
#pragma unroll
    for (int k = 0; k < 8; ++k) {
        float s = sig[k] * t6[k];
#pragma unroll
        for (int j = 0; j < k; ++j) s = fmaf(-M[k][j], w[j], s);
        w[k] = s * ldia[k];
        ssq  = fmaf(w[k], w[k], ssq);
    }
    float mahal  = qdr - ssq;
    float logdet = slr + logdetM;
    float alpha  = -0.5f * (mahal + logdet + 29.40603306254952f); // 16*ln(2pi)

    // ---- gamma: V = (diag(Sinv)+1e-6 I + G8)^-1 ----
    float Vi[8][8];
#pragma unroll
    for (int k = 0; k < 8; ++k)
#pragma unroll
        for (int l = 0; l <= k; ++l)
            Vi[k][l] = G8[k * 8 + l] + ((k == l) ? (Sinv[k] + 1e-6f) : 0.0f);

    float vdia[8];
#pragma unroll
    for (int k = 0; k < 8; ++k) {
        float d = Vi[k][k];
#pragma unroll
        for (int j = 0; j < k; ++j) d = fmaf(-Vi[k][j], Vi[k][j], d);
        float l = sqrtf(d);
        float li = rcp1(l);
        Vi[k][k] = l; vdia[k] = li;
#pragma unroll
        for (int i = k + 1; i < 8; ++i) {
            float s = Vi[i][k];
#pragma unroll
            for (int j = 0; j < k; ++j) s = fmaf(-Vi[i][j], Vi[k][j], s);
            Vi[i][k] = s * li;
        }
    }
    // J = L^-1 (lower), stored into M (dead)
#pragma unroll
    for (int k = 0; k < 8; ++k) {
        M[k][k] = vdia[k];
#pragma unroll
        for (int i = k + 1; i < 8; ++i) {
            float s = 0.0f;
#pragma unroll
            for (int j = k; j < i; ++j) s = fmaf(Vi[i][j], M[j][k], s);
            M[i][k] = -s * vdia[i];
        }
    }
    float info[8];
#pragma unroll
    for (int k = 0; k < 8; ++k) info[k] = fmaf(Sinv[k], mu[k], t8[k]);

    // ---- V = J^T J + gamma, staged through LDS (reuse hn) in 4 chunks ----
    __syncthreads();
#pragma unroll 1
    for (int ch = 0; ch < 4; ++ch) {
        if (wv == ch) {
            float gam[8];
#pragma unroll
            for (int a = 0; a < 8; ++a) gam[a] = 0.0f;
#pragma unroll
            for (int a = 0; a < 8; ++a) {
#pragma unroll
                for (int b = 0; b < 8; ++b) {
                    int m0 = (a > b) ? a : b;
                    float s = 0.0f;
#pragma unroll
                    for (int i = 0; i < 8; ++i)
                        if (i >= m0) s = fmaf(M[i][a], M[i][b], s);
                    hn[(a * 8 + b) * 65 + lane] = s;
                    gam[a] = fmaf(s, info[b], gam[a]);
                }
            }
            out[e] = alpha;
            float4* outG = (float4*)(out + (size_t)BATCH + e * 8);
            outG[0] = make_float4(gam[0], gam[1], gam[2], gam[3]);
            outG[1] = make_float4(gam[4], gam[5], gam[6], gam[7]);
        }
        __syncthreads();
        {
            float* outV = out + (size_t)BATCH * 9 + ((size_t)blk * 256 + (size_t)ch * 64) * 64;
#pragma unroll
            for (int i = 0; i < 4; ++i) {
                int g = i * 1024 + t * 4;
                int ee = g >> 6, j = g & 63;
                float4 v = make_float4(hn[(j + 0) * 65 + ee], hn[(j + 1) * 65 + ee],
                                       hn[(j + 2) * 65 + ee], hn[(j + 3) * 65 + ee]);
                *(float4*)(outV + g) = v;
            }
        }
        __syncthreads();
    }
}

extern "C" void kernel_launch(void* const* d_in, const int* in_sizes, int n_in,
                              void* d_out, int out_size, void* d_ws, size_t ws_size,
                              hipStream_t stream) {
    const float* h    = (const float*)d_in[0];
    const float* c    = (const float*)d_in[1];
    const float* zp   = (const float*)d_in[2];
    const float* xt   = (const float*)d_in[3];
    const float* Wk   = (const float*)d_in[4];
    const float* Wr   = (const float*)d_in[5];
    const float* bl   = (const float*)d_in[6];
    const float* Wmu  = (const float*)d_in[7];
    const float* bmu  = (const float*)d_in[8];
    const float* Wls  = (const float*)d_in[9];
    const float* bls  = (const float*)d_in[10];
    const float* Cm   = (const float*)d_in[11];
    const float* bem  = (const float*)d_in[12];
    const float* logR = (const float*)d_in[13];
    float* ws  = (float*)d_ws;
    float* out = (float*)d_out;

    hipLaunchKernelGGL(prep_kernel, dim3(1), dim3(256), 0, stream, Wk, Wr, bl, Cm, logR, ws);
    hipLaunchKernelGGL(lstm_kernel, dim3(BATCH / 64), dim3(256), 0, stream,
                       h, c, zp, ws, out);
    hipLaunchKernelGGL(tail_kernel, dim3(BATCH / 256), dim3(256), 0, stream,
                       xt, Wmu, bmu, Wls, bls, Cm, bem, ws, out);
}

// Round 7
// 397.359 us; speedup vs baseline: 3.4338x; 3.4338x over previous
//
#include <hip/hip_runtime.h>
#include <math.h>

// Problem constants
#define BATCH 262144

// ws layout (float offsets)
#define WF_OFF  0        // [72][256] gate-interleaved fused weights: W_fused[k][u*4+g]
#define BF_OFF  18432    // [256] gate-interleaved bias b_fused[u*4+g]
#define G6_OFF  18944    // [8][8]  C^T diag(1/(R+1e-6)) C
#define G8_OFF  19008    // [8][8]  C^T diag(1/(R+1e-8)) C
#define R6_OFF  19072    // [16] 1/(R+1e-6)
#define R8_OFF  19088    // [16] 1/(R+1e-8)
#define SLR_OFF 19104    // scalar: sum log(R+1e-6)

__device__ __forceinline__ float rcp1(float x) {
    float r = __builtin_amdgcn_rcpf(x);
    return r * (2.0f - x * r);   // one Newton step: ~1e-7 rel err
}
__device__ __forceinline__ float sigm(float x) {
    float e = __expf(-fabsf(x));          // in (0,1], never overflows
    float s = rcp1(1.0f + e);             // sigm(|x|)
    return (x >= 0.0f) ? s : e * s;       // sigm(-|x|) = e*s
}
__device__ __forceinline__ float tanh_f(float x) {
    float e = __expf(-2.0f * fabsf(x));   // in (0,1]
    float t = (1.0f - e) * rcp1(1.0f + e);
    return copysignf(t, x);
}

// ---------------- prep: fuse/permute weights + batch-independent stats -------
__global__ void prep_kernel(const float* __restrict__ Wk,   // [8][256]
                            const float* __restrict__ Wr,   // [64][256]
                            const float* __restrict__ b_lstm,// [256]
                            const float* __restrict__ Cm,   // [16][8]
                            const float* __restrict__ logR, // [16]
                            float* __restrict__ ws) {
    int t = threadIdx.x;   // 0..255 = fused column c = u*4 + g
    int src = (t & 3) * 64 + (t >> 2);   // original column g*64+u
#pragma unroll
    for (int k = 0; k < 8; ++k)  ws[WF_OFF + k * 256 + t]       = Wk[k * 256 + src];
#pragma unroll
    for (int k = 0; k < 64; ++k) ws[WF_OFF + (8 + k) * 256 + t] = Wr[k * 256 + src];
    ws[BF_OFF + t] = b_lstm[src];

    if (t < 64) {
        int k = t >> 3, l = t & 7;
        float g6 = 0.0f, g8 = 0.0f;
        for (int i = 0; i < 16; ++i) {
            float R  = expf(logR[i]);
            float cc = Cm[i * 8 + k] * Cm[i * 8 + l];
            g6 += cc / (R + 1e-6f);
            g8 += cc / (R + 1e-8f);
        }
        ws[G6_OFF + t] = g6;
        ws[G8_OFF + t] = g8;
    } else if (t < 80) {
        int i = t - 64;
        float R = expf(logR[i]);
        ws[R6_OFF + i] = 1.0f / (R + 1e-6f);
        ws[R8_OFF + i] = 1.0f / (R + 1e-8f);
    } else if (t == 80) {
        float s = 0.0f;
        for (int i = 0; i < 16; ++i) s += logf(expf(logR[i]) + 1e-6f);
        ws[SLR_OFF] = s;
    }
}

// ---------------- LSTM kernel: register-tiled GEMM, conflict-free LDS --------
// Block = 256 threads, tile = 64 elements x 256 gate-cols, per-thread 8x8.
// mt = t>>5 (elem group), nt = t&31. Thread owns units u0=nt, u1=nt+32 ->
// B-reads are LINEAR 512B spans (chunks 0..31 / 32..63) -> conflict-free
// (verified round 5: SQ_LDS_BANK_CONFLICT = 0).
// ha staged ROW-major [e][72] (linear float4 writes; A-reads are broadcast).
// LDS = 18432 + 12288 = 30720 B. __launch_bounds__(256,4): VGPR cap 128
// (kernel needs ~100; round-5's (256,5) clamped to 48 -> acc spill disaster).
__global__ __launch_bounds__(256, 4)
void lstm_kernel(const float* __restrict__ h_in,
                 const float* __restrict__ c_in,
                 const float* __restrict__ z_prev,
                 const float* __restrict__ ws,
                 float* __restrict__ out) {
    __shared__ __align__(16) float ha_lds[64 * 72];  // [e][k]: 0-7 z, 8-71 h; reused as c/h buf [64][64]
    __shared__ __align__(16) float w_lds[12 * 256];  // K-chunk of W_fused

    const int t  = threadIdx.x;
    const int mt = t >> 5;     // 0..7
    const int nt = t & 31;     // 0..31
    const int u0 = nt;
    const int u1 = nt + 32;
    const size_t E0 = (size_t)blockIdx.x * 64;
    const float* WF = ws + WF_OFF;

    // ---- stage ha row-major (all linear float4 LDS writes) ----
#pragma unroll
    for (int i = 0; i < 4; ++i) {
        int g = i * 1024 + t * 4;      // 0..4095
        int e = g >> 6, u = g & 63;
        float4 hv = *(const float4*)(h_in + E0 * 64 + g);
        *(float4*)(ha_lds + e * 72 + 8 + u) = hv;
    }
    if (t < 128) {
        int g = t * 4;                 // 0..511
        int e = g >> 3, p = g & 7;
        float4 zv = *(const float4*)(z_prev + E0 * 8 + g);
        *(float4*)(ha_lds + e * 72 + p) = zv;
    }

    float acc[8][8];
#pragma unroll
    for (int j = 0; j < 8; ++j)
#pragma unroll
        for (int c = 0; c < 8; ++c) acc[j][c] = 0.0f;

    // ---- GEMM over K in 6 chunks of 12 ----
#pragma unroll 1
    for (int ch = 0; ch < 6; ++ch) {
        __syncthreads();   // ha staged (ch 0) / previous chunk FMAs done
#pragma unroll
        for (int i = 0; i < 3; ++i) {
            int off = (i * 256 + t) * 4;
            *(float4*)(w_lds + off) = *(const float4*)(WF + ch * (12 * 256) + off);
        }
        __syncthreads();
#pragma unroll
        for (int k4 = 0; k4 < 12; k4 += 4) {
            float4 av[8];
#pragma unroll
            for (int j = 0; j < 8; ++j)
                av[j] = *(const float4*)(ha_lds + (mt * 8 + j) * 72 + ch * 12 + k4);
#pragma unroll
            for (int kk = 0; kk < 4; ++kk) {
                float4 b0 = *(const float4*)(w_lds + (k4 + kk) * 256 + u0 * 4);
                float4 b1 = *(const float4*)(w_lds + (k4 + kk) * 256 + u1 * 4);
#pragma unroll
                for (int j = 0; j < 8; ++j) {
                    float a = (kk == 0) ? av[j].x : (kk == 1) ? av[j].y : (kk == 2) ? av[j].z : av[j].w;
                    acc[j][0] = fmaf(a, b0.x, acc[j][0]);
                    acc[j][1] = fmaf(a, b0.y, acc[j][1]);
                    acc[j][2] = fmaf(a, b0.z, acc[j][2]);
                    acc[j][3] = fmaf(a, b0.w, acc[j][3]);
                    acc[j][4] = fmaf(a, b1.x, acc[j][4]);
                    acc[j][5] = fmaf(a, b1.y, acc[j][5]);
                    acc[j][6] = fmaf(a, b1.z, acc[j][6]);
                    acc[j][7] = fmaf(a, b1.w, acc[j][7]);
                }
            }
        }
    }
    __syncthreads();   // GEMM done; ha_lds / w_lds reusable

    // ---- load c_old into LDS (short live range: load -> immediate store) ----
    float* cbuf = ha_lds;   // [64][64] row-major
    {
        float4 ctmp[4];
#pragma unroll
        for (int i = 0; i < 4; ++i)
            ctmp[i] = *(const float4*)(c_in + E0 * 64 + i * 1024 + t * 4);
#pragma unroll
        for (int i = 0; i < 4; ++i)
            *(float4*)(cbuf + i * 1024 + t * 4) = ctmp[i];
    }
    __syncthreads();

    // ---- nonlinearity in-register: thread owns (u0,u1) x elems mt*8..+7 ----
    const float* BF = ws + BF_OFF;
    const float bi0 = BF[u0 * 4 + 0], bf0 = BF[u0 * 4 + 1], bg0 = BF[u0 * 4 + 2], bo0 = BF[u0 * 4 + 3];
    const float bi1 = BF[u1 * 4 + 0], bf1 = BF[u1 * 4 + 1], bg1 = BF[u1 * 4 + 2], bo1 = BF[u1 * 4 + 3];
    float hn0[8], hn1[8];
#pragma unroll
    for (int j = 0; j < 8; ++j) {
        int e = mt * 8 + j;
        {
            float zi = acc[j][0] + bi0, zf = acc[j][1] + bf0;
            float zg = acc[j][2] + bg0, zo = acc[j][3] + bo0;
            float cold = cbuf[e * 64 + u0];
            float cn = sigm(zf) * cold + sigm(zi) * tanh_f(zg);
            hn0[j] = sigm(zo) * tanh_f(cn);
            cbuf[e * 64 + u0] = cn;   // slot's only reader is this thread
        }
        {
            float zi = acc[j][4] + bi1, zf = acc[j][5] + bf1;
            float zg = acc[j][6] + bg1, zo = acc[j][7] + bo1;
            float cold = cbuf[e * 64 + u1];
            float cn = sigm(zf) * cold + sigm(zi) * tanh_f(zg);
            hn1[j] = sigm(zo) * tanh_f(cn);
            cbuf[e * 64 + u1] = cn;
        }
    }
    __syncthreads();

    // ---- write out c_new (coalesced), then reuse cbuf for h_new ----
    float* outH = out + (size_t)BATCH * 73  + E0 * 64;
    float* outC = out + (size_t)BATCH * 137 + E0 * 64;
#pragma unroll
    for (int i = 0; i < 4; ++i) {
        int g = i * 1024 + t * 4;
        *(float4*)(outC + g) = *(const float4*)(cbuf + g);
    }
    __syncthreads();
#pragma unroll
    for (int j = 0; j < 8; ++j) {
        int e = mt * 8 + j;
        cbuf[e * 64 + u0] = hn0[j];
        cbuf[e * 64 + u1] = hn1[j];
    }
    __syncthreads();
#pragma unroll
    for (int i = 0; i < 4; ++i) {
        int g = i * 1024 + t * 4;
        *(float4*)(outH + g) = *(const float4*)(cbuf + g);
    }
}

// ---------------- tail kernel: mu/lsg GEMM + Gaussian tail -------------------
__global__ __launch_bounds__(256)
void tail_kernel(const float* __restrict__ x_in,
                 const float* __restrict__ W_mu,
                 const float* __restrict__ b_mu,
                 const float* __restrict__ W_ls,
                 const float* __restrict__ b_ls,
                 const float* __restrict__ Cm,
                 const float* __restrict__ b_em,
                 const float* __restrict__ ws,
                 float* __restrict__ out) {
    __shared__ float hn[64 * 65];     // [u][e] h_new tile; reused as V chunk buffer
    __shared__ float muls[16 * 257];  // [d][e256]

    const int t    = threadIdx.x;
    const int lane = t & 63;
    const int wv   = t >> 6;
    const int wvu  = __builtin_amdgcn_readfirstlane(wv);
    const int blk  = blockIdx.x;
    const float* hN = out + (size_t)BATCH * 73;

    for (int tile = 0; tile < 4; ++tile) {
        const size_t E0 = (size_t)blk * 256 + (size_t)tile * 64;
#pragma unroll
        for (int i = 0; i < 4; ++i) {
            int g = i * 1024 + t * 4;
            int e = g >> 6, u = g & 63;
            float4 hv = *(const float4*)(hN + E0 * 64 + g);
            hn[(u + 0) * 65 + e] = hv.x;
            hn[(u + 1) * 65 + e] = hv.y;
            hn[(u + 2) * 65 + e] = hv.z;
            hn[(u + 3) * 65 + e] = hv.w;
        }
        __syncthreads();
        {
            int d0 = wvu * 2;
            float m0 = b_mu[d0], m1 = b_mu[d0 + 1];
            float l0 = b_ls[d0], l1 = b_ls[d0 + 1];
#pragma unroll
            for (int u = 0; u < 64; ++u) {
                float hv = hn[u * 65 + lane];
                m0 = fmaf(hv, W_mu[u * 8 + d0],     m0);
                m1 = fmaf(hv, W_mu[u * 8 + d0 + 1], m1);
                l0 = fmaf(hv, W_ls[u * 8 + d0],     l0);
                l1 = fmaf(hv, W_ls[u * 8 + d0 + 1], l1);
            }
            int col = tile * 64 + lane;
            muls[(d0 + 0) * 257 + col] = m0;
            muls[(d0 + 1) * 257 + col] = m1;
            muls[(8 + d0 + 0) * 257 + col] = l0;
            muls[(8 + d0 + 1) * 257 + col] = l1;
        }
        __syncthreads();
    }

    const float* G6 = ws + G6_OFF;
    const float* G8 = ws + G8_OFF;
    const float* r6 = ws + R6_OFF;
    const float* r8 = ws + R8_OFF;
    const float  slr = ws[SLR_OFF];
    const size_t e = (size_t)blk * 256 + t;

    float mu[8], lsg[8];
#pragma unroll
    for (int d = 0; d < 8; ++d) {
        mu[d]  = muls[d * 257 + t];
        lsg[d] = muls[(8 + d) * 257 + t];
    }

    float sig[8], Sinv[8];
#pragma unroll
    for (int d = 0; d < 8; ++d) {
        float l = fminf(fmaxf(lsg[d], -5.0f), 3.0f);
        float s = __expf(l);
        sig[d]  = s;
        Sinv[d] = rcp1(s * s + 1e-8f);
    }

    float xv[16];
    {
        const float4* x4 = (const float4*)(x_in + e * 16);
#pragma unroll
        for (int q = 0; q < 4; ++q) {
            float4 v = x4[q];
            xv[4 * q + 0] = v.x; xv[4 * q + 1] = v.y;
            xv[4 * q + 2] = v.z; xv[4 * q + 3] = v.w;
        }
    }

    float t6[8], t8[8];
#pragma unroll
    for (int k = 0; k < 8; ++k) { t6[k] = 0.0f; t8[k] = 0.0f; }
    float qdr = 0.0f;
#pragma unroll
    for (int i = 0; i < 16; ++i) {
        float pm = b_em[i];
#pragma unroll
        for (int d = 0; d < 8; ++d) pm = fmaf(mu[d], Cm[i * 8 + d], pm);
        float df = xv[i] - pm;
        float xe = xv[i] - b_em[i];
        float a6 = df * r6[i];
        float a8 = xe * r8[i];
        qdr = fmaf(df, a6, qdr);
#pragma unroll
        for (int k = 0; k < 8; ++k) {
            t6[k] = fmaf(a6, Cm[i * 8 + k], t6[k]);
            t8[k] = fmaf(a8, Cm[i * 8 + k], t8[k]);
        }
    }

    // ---- alpha via Woodbury ----
    float M[8][8];
#pragma unroll
    for (int k = 0; k < 8; ++k)
#pragma unroll
        for (int l = 0; l <= k; ++l)
            M[k][l] = ((k == l) ? 1.0f : 0.0f) + sig[k] * sig[l] * G6[k * 8 + l];

    float ldia[8];
    float logdetM = 0.0f;
#pragma unroll
    for (int k = 0; k < 8; ++k) {
        float d = M[k][k];
#pragma unroll
        for (int j = 0; j < k; ++j) d = fmaf(-M[k][j], M[k][j], d);
        float l = sqrtf(d);
        logdetM += __logf(d);
        float li = rcp1(l);
        M[k][k] = l; ldia[k] = li;
#pragma unroll
        for (int i = k + 1; i < 8; ++i) {
            float s = M[i][k];
#pragma unroll
            for (int j = 0; j < k; ++j) s = fmaf(-M[i][j], M[k][j], s);
            M[i][k] = s * li;
        }
    }
    float w[8];
    float ssq = 0.0f;
#pragma unroll
    for (int k = 0; k < 8; ++k) {
        float s = sig[k] * t6[k];
#pragma unroll
        for (int j = 0; j < k; ++j) s = fmaf(-M[k][j], w[j], s);
        w[k] = s * ldia[k];
        ssq  = fmaf(w[k], w[k], ssq);
    }
    float mahal  = qdr - ssq;
    float logdet = slr + logdetM;
    float alpha  = -0.5f * (mahal + logdet + 29.40603306254952f); // 16*ln(2pi)

    // ---- gamma: V = (diag(Sinv)+1e-6 I + G8)^-1 ----
    float Vi[8][8];
#pragma unroll
    for (int k = 0; k < 8; ++k)
#pragma unroll
        for (int l = 0; l <= k; ++l)
            Vi[k][l] = G8[k * 8 + l] + ((k == l) ? (Sinv[k] + 1e-6f) : 0.0f);

    float vdia[8];
#pragma unroll
    for (int k = 0; k < 8; ++k) {
        float d = Vi[k][k];
#pragma unroll
        for (int j = 0; j < k; ++j) d = fmaf(-Vi[k][j], Vi[k][j], d);
        float l = sqrtf(d);
        float li = rcp1(l);
        Vi[k][k] = l; vdia[k] = li;
#pragma unroll
        for (int i = k + 1; i < 8; ++i) {
            float s = Vi[i][k];
#pragma unroll
            for (int j = 0; j < k; ++j) s = fmaf(-Vi[i][j], Vi[k][j], s);
            Vi[i][k] = s * li;
        }
    }
    // J = L^-1 (lower), stored into M (dead)
#pragma unroll
    for (int k = 0; k < 8; ++k) {
        M[k][k] = vdia[k];
#pragma unroll
        for (int i = k + 1; i < 8; ++i) {
            float s = 0.0f;
#pragma unroll
            for (int j = k; j < i; ++j) s = fmaf(Vi[i][j], M[j][k], s);
            M[i][k] = -s * vdia[i];
        }
    }
    float info[8];
#pragma unroll
    for (int k = 0; k < 8; ++k) info[k] = fmaf(Sinv[k], mu[k], t8[k]);

    // ---- V = J^T J + gamma, staged through LDS (reuse hn) in 4 chunks ----
    __syncthreads();
#pragma unroll 1
    for (int ch = 0; ch < 4; ++ch) {
        if (wv == ch) {
            float gam[8];
#pragma unroll
            for (int a = 0; a < 8; ++a) gam[a] = 0.0f;
#pragma unroll
            for (int a = 0; a < 8; ++a) {
#pragma unroll
                for (int b = 0; b < 8; ++b) {
                    int m0 = (a > b) ? a : b;
                    float s = 0.0f;
#pragma unroll
                    for (int i = 0; i < 8; ++i)
                        if (i >= m0) s = fmaf(M[i][a], M[i][b], s);
                    hn[(a * 8 + b) * 65 + lane] = s;
                    gam[a] = fmaf(s, info[b], gam[a]);
                }
            }
            out[e] = alpha;
            float4* outG = (float4*)(out + (size_t)BATCH + e * 8);
            outG[0] = make_float4(gam[0], gam[1], gam[2], gam[3]);
            outG[1] = make_float4(gam[4], gam[5], gam[6], gam[7]);
        }
        __syncthreads();
        {
            float* outV = out + (size_t)BATCH * 9 + ((size_t)blk * 256 + (size_t)ch * 64) * 64;
#pragma unroll
            for (int i = 0; i < 4; ++i) {
                int g = i * 1024 + t * 4;
                int ee = g >> 6, j = g & 63;
                float4 v = make_float4(hn[(j + 0) * 65 + ee], hn[(j + 1) * 65 + ee],
                                       hn[(j + 2) * 65 + ee], hn[(j + 3) * 65 + ee]);
                *(float4*)(outV + g) = v;
            }
        }
        __syncthreads();
    }
}

extern "C" void kernel_launch(void* const* d_in, const int* in_sizes, int n_in,
                              void* d_out, int out_size, void* d_ws, size_t ws_size,
                              hipStream_t stream) {
    const float* h    = (const float*)d_in[0];
    const float* c    = (const float*)d_in[1];
    const float* zp   = (const float*)d_in[2];
    const float* xt   = (const float*)d_in[3];
    const float* Wk   = (const float*)d_in[4];
    const float* Wr   = (const float*)d_in[5];
    const float* bl   = (const float*)d_in[6];
    const float* Wmu  = (const float*)d_in[7];
    const float* bmu  = (const float*)d_in[8];
    const float* Wls  = (const float*)d_in[9];
    const float* bls  = (const float*)d_in[10];
    const float* Cm   = (const float*)d_in[11];
    const float* bem  = (const float*)d_in[12];
    const float* logR = (const float*)d_in[13];
    float* ws  = (float*)d_ws;
    float* out = (float*)d_out;

    hipLaunchKernelGGL(prep_kernel, dim3(1), dim3(256), 0, stream, Wk, Wr, bl, Cm, logR, ws);
    hipLaunchKernelGGL(lstm_kernel, dim3(BATCH / 64), dim3(256), 0, stream,
                       h, c, zp, ws, out);
    hipLaunchKernelGGL(tail_kernel, dim3(BATCH / 256), dim3(256), 0, stream,
                       xt, Wmu, bmu, Wls, bls, Cm, bem, ws, out);
}

// Round 8
// 225.564 us; speedup vs baseline: 6.0491x; 1.7616x over previous
//
#include <hip/hip_runtime.h>
#include <math.h>

// Problem constants
#define BATCH 262144

// ws layout (float offsets)
#define WF_OFF  0        // [72][256] gate-interleaved fused weights: W_fused[k][u*4+g]
#define BF_OFF  18432    // [256] gate-interleaved bias b_fused[u*4+g]
#define G6_OFF  18944    // [8][8]  C^T diag(1/(R+1e-6)) C
#define G8_OFF  19008    // [8][8]  C^T diag(1/(R+1e-8)) C
#define R6_OFF  19072    // [16] 1/(R+1e-6)
#define R8_OFF  19088    // [16] 1/(R+1e-8)
#define SLR_OFF 19104    // scalar: sum log(R+1e-6)

__device__ __forceinline__ float rcp1(float x) {
    float r = __builtin_amdgcn_rcpf(x);
    return r * (2.0f - x * r);   // one Newton step: ~1e-7 rel err
}
__device__ __forceinline__ float sigm(float x) {
    float e = __expf(-fabsf(x));          // in (0,1], never overflows
    float s = rcp1(1.0f + e);             // sigm(|x|)
    return (x >= 0.0f) ? s : e * s;       // sigm(-|x|) = e*s
}
__device__ __forceinline__ float tanh_f(float x) {
    float e = __expf(-2.0f * fabsf(x));   // in (0,1]
    float t = (1.0f - e) * rcp1(1.0f + e);
    return copysignf(t, x);
}

// ---------------- prep: fuse/permute weights + batch-independent stats -------
__global__ void prep_kernel(const float* __restrict__ Wk,   // [8][256]
                            const float* __restrict__ Wr,   // [64][256]
                            const float* __restrict__ b_lstm,// [256]
                            const float* __restrict__ Cm,   // [16][8]
                            const float* __restrict__ logR, // [16]
                            float* __restrict__ ws) {
    int t = threadIdx.x;   // 0..255 = fused column c = u*4 + g
    int src = (t & 3) * 64 + (t >> 2);   // original column g*64+u
#pragma unroll
    for (int k = 0; k < 8; ++k)  ws[WF_OFF + k * 256 + t]       = Wk[k * 256 + src];
#pragma unroll
    for (int k = 0; k < 64; ++k) ws[WF_OFF + (8 + k) * 256 + t] = Wr[k * 256 + src];
    ws[BF_OFF + t] = b_lstm[src];

    if (t < 64) {
        int k = t >> 3, l = t & 7;
        float g6 = 0.0f, g8 = 0.0f;
        for (int i = 0; i < 16; ++i) {
            float R  = expf(logR[i]);
            float cc = Cm[i * 8 + k] * Cm[i * 8 + l];
            g6 += cc / (R + 1e-6f);
            g8 += cc / (R + 1e-8f);
        }
        ws[G6_OFF + t] = g6;
        ws[G8_OFF + t] = g8;
    } else if (t < 80) {
        int i = t - 64;
        float R = expf(logR[i]);
        ws[R6_OFF + i] = 1.0f / (R + 1e-6f);
        ws[R8_OFF + i] = 1.0f / (R + 1e-8f);
    } else if (t == 80) {
        float s = 0.0f;
        for (int i = 0; i < 16; ++i) s += logf(expf(logR[i]) + 1e-6f);
        ws[SLR_OFF] = s;
    }
}

// ---------------- LSTM kernel: register-tiled GEMM, conflict-free LDS --------
// Block = 256 threads, tile = 64 elements x 256 gate-cols, per-thread 8x8.
// mt = t>>5 (elem group), nt = t&31. Thread owns units u0=nt, u1=nt+32 ->
// B-reads are LINEAR 512B spans -> conflict-free (r5: SQ_LDS_BANK_CONFLICT=0).
// ha staged ROW-major [e][72] (linear float4 writes; A-reads are broadcast).
// __launch_bounds__(256) ONLY: this toolchain maps (256,w) to a VGPR cap of
// ~256/w (r5: w=5->48, r6: w=4->64), spilling the 64-reg acc. Unconstrained
// allocation gives ~100 VGPR (r4) -> no spill, 4 waves/SIMD.
__global__ __launch_bounds__(256)
void lstm_kernel(const float* __restrict__ h_in,
                 const float* __restrict__ c_in,
                 const float* __restrict__ z_prev,
                 const float* __restrict__ ws,
                 float* __restrict__ out) {
    __shared__ __align__(16) float ha_lds[64 * 72];  // [e][k]: 0-7 z, 8-71 h; reused as c/h buf [64][64]
    __shared__ __align__(16) float w_lds[12 * 256];  // K-chunk of W_fused

    const int t  = threadIdx.x;
    const int mt = t >> 5;     // 0..7
    const int nt = t & 31;     // 0..31
    const int u0 = nt;
    const int u1 = nt + 32;
    const size_t E0 = (size_t)blockIdx.x * 64;
    const float* WF = ws + WF_OFF;

    // ---- stage ha row-major (all linear float4 LDS writes) ----
#pragma unroll
    for (int i = 0; i < 4; ++i) {
        int g = i * 1024 + t * 4;      // 0..4095
        int e = g >> 6, u = g & 63;
        float4 hv = *(const float4*)(h_in + E0 * 64 + g);
        *(float4*)(ha_lds + e * 72 + 8 + u) = hv;
    }
    if (t < 128) {
        int g = t * 4;                 // 0..511
        int e = g >> 3, p = g & 7;
        float4 zv = *(const float4*)(z_prev + E0 * 8 + g);
        *(float4*)(ha_lds + e * 72 + p) = zv;
    }

    float acc[8][8];
#pragma unroll
    for (int j = 0; j < 8; ++j)
#pragma unroll
        for (int c = 0; c < 8; ++c) acc[j][c] = 0.0f;

    // ---- GEMM over K in 6 chunks of 12 ----
#pragma unroll 1
    for (int ch = 0; ch < 6; ++ch) {
        __syncthreads();   // ha staged (ch 0) / previous chunk FMAs done
#pragma unroll
        for (int i = 0; i < 3; ++i) {
            int off = (i * 256 + t) * 4;
            *(float4*)(w_lds + off) = *(const float4*)(WF + ch * (12 * 256) + off);
        }
        __syncthreads();
#pragma unroll
        for (int k4 = 0; k4 < 12; k4 += 4) {
            float4 av[8];
#pragma unroll
            for (int j = 0; j < 8; ++j)
                av[j] = *(const float4*)(ha_lds + (mt * 8 + j) * 72 + ch * 12 + k4);
#pragma unroll
            for (int kk = 0; kk < 4; ++kk) {
                float4 b0 = *(const float4*)(w_lds + (k4 + kk) * 256 + u0 * 4);
                float4 b1 = *(const float4*)(w_lds + (k4 + kk) * 256 + u1 * 4);
#pragma unroll
                for (int j = 0; j < 8; ++j) {
                    float a = (kk == 0) ? av[j].x : (kk == 1) ? av[j].y : (kk == 2) ? av[j].z : av[j].w;
                    acc[j][0] = fmaf(a, b0.x, acc[j][0]);
                    acc[j][1] = fmaf(a, b0.y, acc[j][1]);
                    acc[j][2] = fmaf(a, b0.z, acc[j][2]);
                    acc[j][3] = fmaf(a, b0.w, acc[j][3]);
                    acc[j][4] = fmaf(a, b1.x, acc[j][4]);
                    acc[j][5] = fmaf(a, b1.y, acc[j][5]);
                    acc[j][6] = fmaf(a, b1.z, acc[j][6]);
                    acc[j][7] = fmaf(a, b1.w, acc[j][7]);
                }
            }
        }
    }
    __syncthreads();   // GEMM done; ha_lds / w_lds reusable

    // ---- load c_old into LDS (short live range: load -> immediate store) ----
    float* cbuf = ha_lds;   // [64][64] row-major
    {
        float4 ctmp[4];
#pragma unroll
        for (int i = 0; i < 4; ++i)
            ctmp[i] = *(const float4*)(c_in + E0 * 64 + i * 1024 + t * 4);
#pragma unroll
        for (int i = 0; i < 4; ++i)
            *(float4*)(cbuf + i * 1024 + t * 4) = ctmp[i];
    }
    __syncthreads();

    // ---- nonlinearity in-register: thread owns (u0,u1) x elems mt*8..+7 ----
    const float* BF = ws + BF_OFF;
    const float bi0 = BF[u0 * 4 + 0], bf0 = BF[u0 * 4 + 1], bg0 = BF[u0 * 4 + 2], bo0 = BF[u0 * 4 + 3];
    const float bi1 = BF[u1 * 4 + 0], bf1 = BF[u1 * 4 + 1], bg1 = BF[u1 * 4 + 2], bo1 = BF[u1 * 4 + 3];
    float hn0[8], hn1[8];
#pragma unroll
    for (int j = 0; j < 8; ++j) {
        int e = mt * 8 + j;
        {
            float zi = acc[j][0] + bi0, zf = acc[j][1] + bf0;
            float zg = acc[j][2] + bg0, zo = acc[j][3] + bo0;
            float cold = cbuf[e * 64 + u0];
            float cn = sigm(zf) * cold + sigm(zi) * tanh_f(zg);
            hn0[j] = sigm(zo) * tanh_f(cn);
            cbuf[e * 64 + u0] = cn;   // slot's only reader is this thread
        }
        {
            float zi = acc[j][4] + bi1, zf = acc[j][5] + bf1;
            float zg = acc[j][6] + bg1, zo = acc[j][7] + bo1;
            float cold = cbuf[e * 64 + u1];
            float cn = sigm(zf) * cold + sigm(zi) * tanh_f(zg);
            hn1[j] = sigm(zo) * tanh_f(cn);
            cbuf[e * 64 + u1] = cn;
        }
    }
    __syncthreads();

    // ---- write out c_new (coalesced), then reuse cbuf for h_new ----
    float* outH = out + (size_t)BATCH * 73  + E0 * 64;
    float* outC = out + (size_t)BATCH * 137 + E0 * 64;
#pragma unroll
    for (int i = 0; i < 4; ++i) {
        int g = i * 1024 + t * 4;
        *(float4*)(outC + g) = *(const float4*)(cbuf + g);
    }
    __syncthreads();
#pragma unroll
    for (int j = 0; j < 8; ++j) {
        int e = mt * 8 + j;
        cbuf[e * 64 + u0] = hn0[j];
        cbuf[e * 64 + u1] = hn1[j];
    }
    __syncthreads();
#pragma unroll
    for (int i = 0; i < 4; ++i) {
        int g = i * 1024 + t * 4;
        *(float4*)(outH + g) = *(const float4*)(cbuf + g);
    }
}

// ---------------- tail kernel: mu/lsg GEMM + Gaussian tail -------------------
__global__ __launch_bounds__(256)
void tail_kernel(const float* __restrict__ x_in,
                 const float* __restrict__ W_mu,
                 const float* __restrict__ b_mu,
                 const float* __restrict__ W_ls,
                 const float* __restrict__ b_ls,
                 const float* __restrict__ Cm,
                 const float* __restrict__ b_em,
                 const float* __restrict__ ws,
                 float* __restrict__ out) {
    __shared__ float hn[64 * 65];     // [u][e] h_new tile; reused as V chunk buffer
    __shared__ float muls[16 * 257];  // [d][e256]

    const int t    = threadIdx.x;
    const int lane = t & 63;
    const int wv   = t >> 6;
    const int wvu  = __builtin_amdgcn_readfirstlane(wv);
    const int blk  = blockIdx.x;
    const float* hN = out + (size_t)BATCH * 73;

    for (int tile = 0; tile < 4; ++tile) {
        const size_t E0 = (size_t)blk * 256 + (size_t)tile * 64;
#pragma unroll
        for (int i = 0; i < 4; ++i) {
            int g = i * 1024 + t * 4;
            int e = g >> 6, u = g & 63;
            float4 hv = *(const float4*)(hN + E0 * 64 + g);
            hn[(u + 0) * 65 + e] = hv.x;
            hn[(u + 1) * 65 + e] = hv.y;
            hn[(u + 2) * 65 + e] = hv.z;
            hn[(u + 3) * 65 + e] = hv.w;
        }
        __syncthreads();
        {
            int d0 = wvu * 2;
            float m0 = b_mu[d0], m1 = b_mu[d0 + 1];
            float l0 = b_ls[d0], l1 = b_ls[d0 + 1];
#pragma unroll
            for (int u = 0; u < 64; ++u) {
                float hv = hn[u * 65 + lane];
                m0 = fmaf(hv, W_mu[u * 8 + d0],     m0);
                m1 = fmaf(hv, W_mu[u * 8 + d0 + 1], m1);
                l0 = fmaf(hv, W_ls[u * 8 + d0],     l0);
                l1 = fmaf(hv, W_ls[u * 8 + d0 + 1], l1);
            }
            int col = tile * 64 + lane;
            muls[(d0 + 0) * 257 + col] = m0;
            muls[(d0 + 1) * 257 + col] = m1;
            muls[(8 + d0 + 0) * 257 + col] = l0;
            muls[(8 + d0 + 1) * 257 + col] = l1;
        }
        __syncthreads();
    }

    const float* G6 = ws + G6_OFF;
    const float* G8 = ws + G8_OFF;
    const float* r6 = ws + R6_OFF;
    const float* r8 = ws + R8_OFF;
    const float  slr = ws[SLR_OFF];
    const size_t e = (size_t)blk * 256 + t;

    float mu[8], lsg[8];
#pragma unroll
    for (int d = 0; d < 8; ++d) {
        mu[d]  = muls[d * 257 + t];
        lsg[d] = muls[(8 + d) * 257 + t];
    }

    float sig[8], Sinv[8];
#pragma unroll
    for (int d = 0; d < 8; ++d) {
        float l = fminf(fmaxf(lsg[d], -5.0f), 3.0f);
        float s = __expf(l);
        sig[d]  = s;
        Sinv[d] = rcp1(s * s + 1e-8f);
    }

    float xv[16];
    {
        const float4* x4 = (const float4*)(x_in + e * 16);
#pragma unroll
        for (int q = 0; q < 4; ++q) {
            float4 v = x4[q];
            xv[4 * q + 0] = v.x; xv[4 * q + 1] = v.y;
            xv[4 * q + 2] = v.z; xv[4 * q + 3] = v.w;
        }
    }

    float t6[8], t8[8];
#pragma unroll
    for (int k = 0; k < 8; ++k) { t6[k] = 0.0f; t8[k] = 0.0f; }
    float qdr = 0.0f;
#pragma unroll
    for (int i = 0; i < 16; ++i) {
        float pm = b_em[i];
#pragma unroll
        for (int d = 0; d < 8; ++d) pm = fmaf(mu[d], Cm[i * 8 + d], pm);
        float df = xv[i] - pm;
        float xe = xv[i] - b_em[i];
        float a6 = df * r6[i];
        float a8 = xe * r8[i];
        qdr = fmaf(df, a6, qdr);
#pragma unroll
        for (int k = 0; k < 8; ++k) {
            t6[k] = fmaf(a6, Cm[i * 8 + k], t6[k]);
            t8[k] = fmaf(a8, Cm[i * 8 + k], t8[k]);
        }
    }

    // ---- alpha via Woodbury ----
    float M[8][8];
#pragma unroll
    for (int k = 0; k < 8; ++k)
#pragma unroll
        for (int l = 0; l <= k; ++l)
            M[k][l] = ((k == l) ? 1.0f : 0.0f) + sig[k] * sig[l] * G6[k * 8 + l];

    float ldia[8];
    float logdetM = 0.0f;
#pragma unroll
    for (int k = 0; k < 8; ++k) {
        float d = M[k][k];
#pragma unroll
        for (int j = 0; j < k; ++j) d = fmaf(-M[k][j], M[k][j], d);
        float l = sqrtf(d);
        logdetM += __logf(d);
        float li = rcp1(l);
        M[k][k] = l; ldia[k] = li;
#pragma unroll
        for (int i = k + 1; i < 8; ++i) {
            float s = M[i][k];
#pragma unroll
            for (int j = 0; j < k; ++j) s = fmaf(-M[i][j], M[k][j], s);
            M[i][k] = s * li;
        }
    }
    float w[8];
    float ssq = 0.0f;
#pragma unroll
    for (int k = 0; k < 8; ++k) {
        float s = sig[k] * t6[k];
#pragma unroll
        for (int j = 0; j < k; ++j) s = fmaf(-M[k][j], w[j], s);
        w[k] = s * ldia[k];
        ssq  = fmaf(w[k], w[k], ssq);
    }
    float mahal  = qdr - ssq;
    float logdet = slr + logdetM;
    float alpha  = -0.5f * (mahal + logdet + 29.40603306254952f); // 16*ln(2pi)

    // ---- gamma: V = (diag(Sinv)+1e-6 I + G8)^-1 ----
    float Vi[8][8];
#pragma unroll
    for (int k = 0; k < 8; ++k)
#pragma unroll
        for (int l = 0; l <= k; ++l)
            Vi[k][l] = G8[k * 8 + l] + ((k == l) ? (Sinv[k] + 1e-6f) : 0.0f);

    float vdia[8];
#pragma unroll
    for (int k = 0; k < 8; ++k) {
        float d = Vi[k][k];
#pragma unroll
        for (int j = 0; j < k; ++j) d = fmaf(-Vi[k][j], Vi[k][j], d);
        float l = sqrtf(d);
        float li = rcp1(l);
        Vi[k][k] = l; vdia[k] = li;
#pragma unroll
        for (int i = k + 1; i < 8; ++i) {
            float s = Vi[i][k];
#pragma unroll
            for (int j = 0; j < k; ++j) s = fmaf(-Vi[i][j], Vi[k][j], s);
            Vi[i][k] = s * li;
        }
    }
    // J = L^-1 (lower), stored into M (dead)
#pragma unroll
    for (int k = 0; k < 8; ++k) {
        M[k][k] = vdia[k];
#pragma unroll
        for (int i = k + 1; i < 8; ++i) {
            float s = 0.0f;
#pragma unroll
            for (int j = k; j < i; ++j) s = fmaf(Vi[i][j], M[j][k], s);
            M[i][k] = -s * vdia[i];
        }
    }
    float info[8];
#pragma unroll
    for (int k = 0; k < 8; ++k) info[k] = fmaf(Sinv[k], mu[k], t8[k]);

    // ---- V = J^T J + gamma, staged through LDS (reuse hn) in 4 chunks ----
    __syncthreads();
#pragma unroll 1
    for (int ch = 0; ch < 4; ++ch) {
        if (wv == ch) {
            float gam[8];
#pragma unroll
            for (int a = 0; a < 8; ++a) gam[a] = 0.0f;
#pragma unroll
            for (int a = 0; a < 8; ++a) {
#pragma unroll
                for (int b = 0; b < 8; ++b) {
                    int m0 = (a > b) ? a : b;
                    float s = 0.0f;
#pragma unroll
                    for (int i = 0; i < 8; ++i)
                        if (i >= m0) s = fmaf(M[i][a], M[i][b], s);
                    hn[(a * 8 + b) * 65 + lane] = s;
                    gam[a] = fmaf(s, info[b], gam[a]);
                }
            }
            out[e] = alpha;
            float4* outG = (float4*)(out + (size_t)BATCH + e * 8);
            outG[0] = make_float4(gam[0], gam[1], gam[2], gam[3]);
            outG[1] = make_float4(gam[4], gam[5], gam[6], gam[7]);
        }
        __syncthreads();
        {
            float* outV = out + (size_t)BATCH * 9 + ((size_t)blk * 256 + (size_t)ch * 64) * 64;
#pragma unroll
            for (int i = 0; i < 4; ++i) {
                int g = i * 1024 + t * 4;
                int ee = g >> 6, j = g & 63;
                float4 v = make_float4(hn[(j + 0) * 65 + ee], hn[(j + 1) * 65 + ee],
                                       hn[(j + 2) * 65 + ee], hn[(j + 3) * 65 + ee]);
                *(float4*)(outV + g) = v;
            }
        }
        __syncthreads();
    }
}

extern "C" void kernel_launch(void* const* d_in, const int* in_sizes, int n_in,
                              void* d_out, int out_size, void* d_ws, size_t ws_size,
                              hipStream_t stream) {
    const float* h    = (const float*)d_in[0];
    const float* c    = (const float*)d_in[1];
    const float* zp   = (const float*)d_in[2];
    const float* xt   = (const float*)d_in[3];
    const float* Wk   = (const float*)d_in[4];
    const float* Wr   = (const float*)d_in[5];
    const float* bl   = (const float*)d_in[6];
    const float* Wmu  = (const float*)d_in[7];
    const float* bmu  = (const float*)d_in[8];
    const float* Wls  = (const float*)d_in[9];
    const float* bls  = (const float*)d_in[10];
    const float* Cm   = (const float*)d_in[11];
    const float* bem  = (const float*)d_in[12];
    const float* logR = (const float*)d_in[13];
    float* ws  = (float*)d_ws;
    float* out = (float*)d_out;

    hipLaunchKernelGGL(prep_kernel, dim3(1), dim3(256), 0, stream, Wk, Wr, bl, Cm, logR, ws);
    hipLaunchKernelGGL(lstm_kernel, dim3(BATCH / 64), dim3(256), 0, stream,
                       h, c, zp, ws, out);
    hipLaunchKernelGGL(tail_kernel, dim3(BATCH / 256), dim3(256), 0, stream,
                       xt, Wmu, bmu, Wls, bls, Cm, bem, ws, out);
}